// Round 4
// baseline (399.951 us; speedup 1.0000x reference)
//
#include <hip/hip_runtime.h>
#include <hip/hip_fp16.h>

#define D 64
#define SZ 512           // nodes per radix bucket (dst>>9 / src>>9)
#define EPB 4096         // edges per scatter block; E<=2^20 -> <=256 blocks
#define CAPB 8192        // slots per bucket region; Binom(1e6,1/196) max ~5500 << 8192
// Assumes N <= 131072 (src fits 17 bits, nb <= 256) and E <= 1048576 (hb <= 256).
// Harness: N=100000, E=1000000.

static __device__ __forceinline__ __half2 u2h2(unsigned u) {
    union { unsigned u; __half2 h; } c; c.u = u; return c.h;
}
static __device__ __forceinline__ unsigned h22u(__half2 h) {
    union { __half2 h; unsigned u; } c; c.h = h; return c.u;
}

// ---------------- A: bucket-partition edges, one kernel, ~96K global atomics ----------
// Pass 1: LDS histogram of this block's 4096 edges. Reserve: one atomicAdd per
// non-empty (block,bucket) into per-bucket cursors (bucket b owns region
// [b*CAPB, (b+1)*CAPB)). Pass 2: LDS-cursor scatter; edge window re-read hits L1/L2.
__global__ __launch_bounds__(256) void scatter_kernel(
    const int* __restrict__ src, const int* __restrict__ dst,
    int* __restrict__ gcntD, int* __restrict__ gcntS,
    unsigned* __restrict__ packD, unsigned short* __restrict__ packS,
    int E, int nb) {
    int tid = threadIdx.x;
    __shared__ int hD[256], hS[256], baseD[256], baseS[256], curD[256], curS[256];
    hD[tid] = 0; hS[tid] = 0; curD[tid] = 0; curS[tid] = 0;
    __syncthreads();
    int ebase = (int)blockIdx.x * EPB;
#pragma unroll
    for (int k = 0; k < EPB / 256; k++) {
        int e = ebase + k * 256 + tid;
        if (e < E) {
            atomicAdd(&hD[dst[e] >> 9], 1);
            atomicAdd(&hS[src[e] >> 9], 1);
        }
    }
    __syncthreads();
    if (tid < nb) {
        int c = hD[tid];
        baseD[tid] = tid * CAPB + (c ? atomicAdd(&gcntD[tid], c) : 0);
        c = hS[tid];
        baseS[tid] = tid * CAPB + (c ? atomicAdd(&gcntS[tid], c) : 0);
    }
    __syncthreads();
#pragma unroll
    for (int k = 0; k < EPB / 256; k++) {
        int e = ebase + k * 256 + tid;
        if (e < E) {
            int s = src[e], d = dst[e];
            int bd = d >> 9, bs_ = s >> 9;
            int ld = atomicAdd(&curD[bd], 1);
            int ls = atomicAdd(&curS[bs_], 1);
            packD[baseD[bd] + ld] = ((unsigned)s << 9) | (unsigned)(d & 511);
            packS[baseS[bs_] + ls] = (unsigned short)(s & 511);
        }
    }
}

// ---------------- B: per-bucket CSR build + norms (coalesced, no scans over buckets) ----
// Blocks [0,nb): dst role -> rowbeg/rowend, csr, in_norm. Blocks [nb,2nb): out_norm.
__global__ __launch_bounds__(256) void build_kernel(
    const unsigned* __restrict__ packD, const unsigned short* __restrict__ packS,
    const int* __restrict__ gcntD, const int* __restrict__ gcntS,
    int* __restrict__ csr, int* __restrict__ rowbeg, int* __restrict__ rowend,
    float* __restrict__ in_norm, float* __restrict__ out_norm,
    int n, int nb) {
    int tid = threadIdx.x;
    __shared__ int cnt[512], lptr[512], tmp[256];
    bool roleD = ((int)blockIdx.x < nb);
    int b = roleD ? (int)blockIdx.x : (int)blockIdx.x - nb;
    int bs = b * CAPB;
    int be = bs + (roleD ? gcntD[b] : gcntS[b]);
    cnt[tid] = 0; cnt[tid + 256] = 0;
    __syncthreads();
    if (roleD) {
        for (int i = bs + tid; i < be; i += 256)
            atomicAdd(&cnt[packD[i] & 511], 1);
        __syncthreads();
        // exclusive scan over 512 node counts (pair trick with 256 threads)
        int a0 = cnt[2 * tid], a1 = cnt[2 * tid + 1];
        tmp[tid] = a0 + a1; __syncthreads();
        for (int off = 1; off < 256; off <<= 1) {
            int u = (tid >= off) ? tmp[tid - off] : 0; __syncthreads();
            tmp[tid] += u; __syncthreads();
        }
        int ex = tmp[tid] - (a0 + a1);
        lptr[2 * tid] = ex; lptr[2 * tid + 1] = ex + a0;
        __syncthreads();
        int v0 = b * SZ + tid, v1 = v0 + 256;
        if (v0 < n) {
            rowbeg[v0] = bs + lptr[tid];
            rowend[v0] = bs + lptr[tid] + cnt[tid];
            in_norm[v0] = rsqrtf((float)max(cnt[tid], 1));
        }
        if (v1 < n) {
            rowbeg[v1] = bs + lptr[tid + 256];
            rowend[v1] = bs + lptr[tid + 256] + cnt[tid + 256];
            in_norm[v1] = rsqrtf((float)max(cnt[tid + 256], 1));
        }
        __syncthreads();
        // fill packed CSR: slots via LDS cursor (lptr consumed)
        for (int i = bs + tid; i < be; i += 256) {
            unsigned p = packD[i];
            int slot = atomicAdd(&lptr[p & 511], 1);
            csr[bs + slot] = (int)(p >> 9);
        }
    } else {
        for (int i = bs + tid; i < be; i += 256)
            atomicAdd(&cnt[packS[i]], 1);
        __syncthreads();
        int v0 = b * SZ + tid, v1 = v0 + 256;
        if (v0 < n) out_norm[v0] = rsqrtf((float)max(cnt[tid], 1));
        if (v1 < n) out_norm[v1] = rsqrtf((float)max(cnt[tid + 256], 1));
    }
}

// ---------------- GEMM: Y = half(scale? * (X @ W)), 64x64 LDS tile, 4x4/thread -------
// Xs layout: 16B-chunk XOR swizzle: chunk kq of row r at Xs[r*64 + ((kq^(r&15))<<2)];
// staging ds_write_b128 and compute ds_read_b128 both <=2-way (free). Ws row-major.
// __launch_bounds__(256,4): cap VGPR at 128 (round-2 lesson: uncapped -> 244 VGPR, 9% occ).
template <int SCALE>
__global__ __launch_bounds__(256, 4) void gemm_kernel(
    const float* __restrict__ X, const float* __restrict__ W,
    const float* __restrict__ scale, __half* __restrict__ P, int n) {
    __shared__ float Ws[64 * 64];
    __shared__ float Xs[64 * 64];
    int tid = threadIdx.x;
    int row0 = (int)blockIdx.x * 64;
    if (row0 >= n) return;
    {
        const float4* W4 = (const float4*)W;
        float4* Ws4 = (float4*)Ws;
#pragma unroll
        for (int i = 0; i < 4; i++) Ws4[tid + 256 * i] = W4[tid + 256 * i];
    }
    {
#pragma unroll
        for (int i = 0; i < 4; i++) {
            int idx = tid + 256 * i;          // 0..1023 = 64 rows x 16 chunks
            int r = idx >> 4, kq = idx & 15;
            float4 v = make_float4(0.f, 0.f, 0.f, 0.f);
            int row = row0 + r;
            if (row < n) v = ((const float4*)X)[(size_t)row * 16 + kq];
            *(float4*)&Xs[r * 64 + ((kq ^ (r & 15)) << 2)] = v;
        }
    }
    __syncthreads();

    int tx = tid & 15, ty = tid >> 4;         // cols 4tx.., rows 4ty..
    float acc[4][4] = {};
#pragma unroll 4
    for (int kc = 0; kc < 16; kc++) {
        float4 wv[4];
#pragma unroll
        for (int j = 0; j < 4; j++) wv[j] = *(float4*)&Ws[(4 * kc + j) * 64 + 4 * tx];
#pragma unroll
        for (int r = 0; r < 4; r++) {
            int row = 4 * ty + r;
            float4 xv = *(float4*)&Xs[row * 64 + ((kc ^ (row & 15)) << 2)];
            acc[r][0] = fmaf(xv.x, wv[0].x, acc[r][0]);
            acc[r][1] = fmaf(xv.x, wv[0].y, acc[r][1]);
            acc[r][2] = fmaf(xv.x, wv[0].z, acc[r][2]);
            acc[r][3] = fmaf(xv.x, wv[0].w, acc[r][3]);
            acc[r][0] = fmaf(xv.y, wv[1].x, acc[r][0]);
            acc[r][1] = fmaf(xv.y, wv[1].y, acc[r][1]);
            acc[r][2] = fmaf(xv.y, wv[1].z, acc[r][2]);
            acc[r][3] = fmaf(xv.y, wv[1].w, acc[r][3]);
            acc[r][0] = fmaf(xv.z, wv[2].x, acc[r][0]);
            acc[r][1] = fmaf(xv.z, wv[2].y, acc[r][1]);
            acc[r][2] = fmaf(xv.z, wv[2].z, acc[r][2]);
            acc[r][3] = fmaf(xv.z, wv[2].w, acc[r][3]);
            acc[r][0] = fmaf(xv.w, wv[3].x, acc[r][0]);
            acc[r][1] = fmaf(xv.w, wv[3].y, acc[r][1]);
            acc[r][2] = fmaf(xv.w, wv[3].z, acc[r][2]);
            acc[r][3] = fmaf(xv.w, wv[3].w, acc[r][3]);
        }
    }
#pragma unroll
    for (int r = 0; r < 4; r++) {
        int row = row0 + 4 * ty + r;
        if (row < n) {
            float sc = SCALE ? scale[row] : 1.f;
            uint2 o;
            o.x = h22u(__floats2half2_rn(acc[r][0] * sc, acc[r][1] * sc));
            o.y = h22u(__floats2half2_rn(acc[r][2] * sc, acc[r][3] * sc));
            *(uint2*)&P[(size_t)row * 64 + 4 * tx] = o;
        }
    }
}

// ---------------- gather: XCD-sliced by feature block ----------------
// Slice fb = blockIdx.x & 3 handles features [16*fb, 16*fb+16) (32B of each fp16 row).
// Consecutive blockIdx round-robin the 8 XCDs, so XCD i only ever touches slice i&3:
// per-XCD hot set = N*32B = 3.2MB < 4MiB L2 -> random row reads become L2 HITS
// (vs. L3 misses when every XCD walked the whole 12.8MB bufP).
// One thread per (node, slice); 16 fp32 accumulators; edge loop 4-wide for ILP
// (8 outstanding 16B loads). Output: 64B contiguous chunk per thread (sector-aligned).
template <int RELU_SCALE>
__global__ __launch_bounds__(256) void gather_kernel(
    const uint4* __restrict__ P4, const int* __restrict__ csr,
    const int* __restrict__ rowbeg, const int* __restrict__ rowend,
    const float* __restrict__ in_norm, const float* __restrict__ out_norm,
    const float* __restrict__ bias, float4* __restrict__ out4, int n) {
    int tid = threadIdx.x;
    int fb = (int)blockIdx.x & 3;
    int v = ((int)blockIdx.x >> 2) * 256 + tid;
    if (v >= n) return;

    int begin = rowbeg[v];
    int end = rowend[v];
    float inv = in_norm[v];
    float sc = RELU_SCALE ? out_norm[v] : 1.f;

    const uint4* Pb = P4 + 2 * fb;     // this slice's 32B within each 128B row

    float a[16];
#pragma unroll
    for (int q = 0; q < 16; q++) a[q] = 0.f;

    for (int e = begin; e < end; e += 4) {
        int j[4];
#pragma unroll
        for (int i = 0; i < 4; i++) {
            int ee = e + i;
            j[i] = (ee < end) ? csr[ee] : -1;
        }
        uint4 t[8];
#pragma unroll
        for (int i = 0; i < 4; i++) {
            t[2 * i] = make_uint4(0u, 0u, 0u, 0u);
            t[2 * i + 1] = make_uint4(0u, 0u, 0u, 0u);
            if (j[i] >= 0) {
                const uint4* p = Pb + (size_t)j[i] * 8;
                t[2 * i] = p[0];
                t[2 * i + 1] = p[1];
            }
        }
#pragma unroll
        for (int i = 0; i < 8; i++) {
            float2 f0 = __half22float2(u2h2(t[i].x));
            float2 f1 = __half22float2(u2h2(t[i].y));
            float2 f2 = __half22float2(u2h2(t[i].z));
            float2 f3 = __half22float2(u2h2(t[i].w));
            int o = (i & 1) * 8;
            a[o + 0] += f0.x; a[o + 1] += f0.y;
            a[o + 2] += f1.x; a[o + 3] += f1.y;
            a[o + 4] += f2.x; a[o + 5] += f2.y;
            a[o + 6] += f3.x; a[o + 7] += f3.y;
        }
    }

    const float4* b4 = (const float4*)bias + 4 * fb;
#pragma unroll
    for (int q = 0; q < 4; q++) {
        float4 bq = b4[q];
        float4 o;
        o.x = fmaf(a[4 * q + 0], inv, bq.x);
        o.y = fmaf(a[4 * q + 1], inv, bq.y);
        o.z = fmaf(a[4 * q + 2], inv, bq.z);
        o.w = fmaf(a[4 * q + 3], inv, bq.w);
        if (RELU_SCALE) {
            o.x = fmaxf(o.x, 0.f) * sc; o.y = fmaxf(o.y, 0.f) * sc;
            o.z = fmaxf(o.z, 0.f) * sc; o.w = fmaxf(o.w, 0.f) * sc;
        }
        out4[(size_t)v * 16 + 4 * fb + q] = o;
    }
}

// ---------------- launch ----------------

extern "C" void kernel_launch(void* const* d_in, const int* in_sizes, int n_in,
                              void* d_out, int out_size, void* d_ws, size_t ws_size,
                              hipStream_t stream) {
    const float* x  = (const float*)d_in[0];
    const int* src  = (const int*)d_in[1];
    const int* dst  = (const int*)d_in[2];
    const float* W1 = (const float*)d_in[3];
    const float* b1 = (const float*)d_in[4];
    const float* W2 = (const float*)d_in[5];
    const float* b2 = (const float*)d_in[6];
    const float* W3 = (const float*)d_in[7];
    const float* b3 = (const float*)d_in[8];

    const int N = in_sizes[0] / D;
    const int E = in_sizes[1];
    const int nb = (N + SZ - 1) / SZ;     // 196 buckets
    const int hb = (E + EPB - 1) / EPB;   // 245 scatter blocks (<=256)

    char* ws = (char*)d_ws;
    size_t off = 0;
    auto alloc = [&](size_t bytes) -> void* {
        void* p = (void*)(ws + off);
        off += (bytes + 15) & ~(size_t)15;
        return p;
    };
    int* gcntD = (int*)alloc(256 * 4);   // contiguous with gcntS: one memset
    int* gcntS = (int*)alloc(256 * 4);
    unsigned* packD       = (unsigned*)alloc((size_t)nb * CAPB * 4);
    unsigned short* packS = (unsigned short*)alloc((size_t)nb * CAPB * 2);
    int* csr     = (int*)alloc((size_t)nb * CAPB * 4);
    int* rowbeg  = (int*)alloc((size_t)N * 4);
    int* rowend  = (int*)alloc((size_t)N * 4);
    float* innrm = (float*)alloc((size_t)N * 4);
    float* outnrm= (float*)alloc((size_t)N * 4);
    __half* bufP = (__half*)alloc((size_t)N * D * 2);  // fp16 transformed feats
    float* bufH  = (float*)alloc((size_t)N * D * 4);   // fp32 hidden state

    const int gemmb = (N + 63) / 64;             // 64-row LDS tiles
    const int sgrid = ((N + 255) / 256) * 4;     // 4 feature slices x node chunks

    hipMemsetAsync(gcntD, 0, 2 * 256 * sizeof(int), stream);

    // A: partition edges into per-bucket regions (~96K global atomics total)
    scatter_kernel<<<hb, 256, 0, stream>>>(src, dst, gcntD, gcntS,
                                           packD, packS, E, nb);
    // B: exact CSR + rowbeg/rowend + both norms, all coalesced
    build_kernel<<<2 * nb, 256, 0, stream>>>(packD, packS, gcntD, gcntS, csr,
                                             rowbeg, rowend, innrm, outnrm, N, nb);

    // layer 1: P1 = half(out_norm * (X @ W1)) — scale fused into GEMM epilogue
    gemm_kernel<1><<<gemmb, 256, 0, stream>>>(x, W1, outnrm, bufP, N);
    gather_kernel<1><<<sgrid, 256, 0, stream>>>((const uint4*)bufP, csr, rowbeg,
                                                rowend, innrm, outnrm, b1,
                                                (float4*)bufH, N);
    // layer 2: h1 already carries out_norm
    gemm_kernel<0><<<gemmb, 256, 0, stream>>>(bufH, W2, nullptr, bufP, N);
    gather_kernel<1><<<sgrid, 256, 0, stream>>>((const uint4*)bufP, csr, rowbeg,
                                                rowend, innrm, outnrm, b2,
                                                (float4*)bufH, N);
    // layer 3: final — no relu, no pre-scale
    gemm_kernel<0><<<gemmb, 256, 0, stream>>>(bufH, W3, nullptr, bufP, N);
    gather_kernel<0><<<sgrid, 256, 0, stream>>>((const uint4*)bufP, csr, rowbeg,
                                                rowend, innrm, outnrm, b3,
                                                (float4*)d_out, N);
}

// Round 5
// 241.587 us; speedup vs baseline: 1.6555x; 1.6555x over previous
//
#include <hip/hip_runtime.h>
#include <hip/hip_fp16.h>

#define D 64
#define SZ 512           // nodes per radix bucket (dst>>9 / src>>9)
#define EPB 1024         // edges per scatter block: 977 blocks -> ~4/CU latency hiding
#define CAPB 8192        // slots per bucket region; Binom(1e6,1/196) max ~5500 << 8192
// Assumes N <= 131072 (src fits 17 bits, nb <= 256). Harness: N=100000, E=1000000.

static __device__ __forceinline__ __half2 u2h2(unsigned u) {
    union { unsigned u; __half2 h; } c; c.u = u; return c.h;
}
static __device__ __forceinline__ unsigned h22u(__half2 h) {
    union { __half2 h; unsigned u; } c; c.h = h; return c.u;
}

// ---------------- A: bucket-partition edges (LDS hist + edge stash, 2 global atomics
// per (block,bucket) only). Bucket b owns region [b*CAPB, (b+1)*CAPB).
__global__ __launch_bounds__(256) void scatter_kernel(
    const int* __restrict__ src, const int* __restrict__ dst,
    int* __restrict__ gcntD, int* __restrict__ gcntS,
    unsigned* __restrict__ packD, unsigned short* __restrict__ packS,
    int E, int nb) {
    int tid = threadIdx.x;
    __shared__ int hD[256], hS[256], baseD[256], baseS[256], curD[256], curS[256];
    __shared__ int es[EPB], ed[EPB];   // edge stash: pass 2 reads LDS, not global
    hD[tid] = 0; hS[tid] = 0; curD[tid] = 0; curS[tid] = 0;
    __syncthreads();
    int ebase = (int)blockIdx.x * EPB;
#pragma unroll
    for (int k = 0; k < EPB / 256; k++) {
        int e = ebase + k * 256 + tid;
        int s = -1, d = 0;
        if (e < E) { s = src[e]; d = dst[e]; }
        es[k * 256 + tid] = s;
        ed[k * 256 + tid] = d;
        if (s >= 0) {
            atomicAdd(&hD[d >> 9], 1);
            atomicAdd(&hS[s >> 9], 1);
        }
    }
    __syncthreads();
    if (tid < nb) {
        int c = hD[tid];
        baseD[tid] = tid * CAPB + (c ? atomicAdd(&gcntD[tid], c) : 0);
        c = hS[tid];
        baseS[tid] = tid * CAPB + (c ? atomicAdd(&gcntS[tid], c) : 0);
    }
    __syncthreads();
#pragma unroll
    for (int k = 0; k < EPB / 256; k++) {
        int s = es[k * 256 + tid];
        if (s >= 0) {
            int d = ed[k * 256 + tid];
            int bd = d >> 9, bs_ = s >> 9;
            int ld = atomicAdd(&curD[bd], 1);
            int ls = atomicAdd(&curS[bs_], 1);
            packD[baseD[bd] + ld] = ((unsigned)s << 9) | (unsigned)(d & 511);
            packS[baseS[bs_] + ls] = (unsigned short)(s & 511);
        }
    }
}

// ---------------- B: per-bucket CSR build + norms (coalesced) ----------------
// Blocks [0,nb): dst role -> rowbeg/rowend, csr, in_norm. Blocks [nb,2nb): out_norm.
__global__ __launch_bounds__(256) void build_kernel(
    const unsigned* __restrict__ packD, const unsigned short* __restrict__ packS,
    const int* __restrict__ gcntD, const int* __restrict__ gcntS,
    int* __restrict__ csr, int* __restrict__ rowbeg, int* __restrict__ rowend,
    float* __restrict__ in_norm, float* __restrict__ out_norm,
    int n, int nb) {
    int tid = threadIdx.x;
    __shared__ int cnt[512], lptr[512], tmp[256];
    bool roleD = ((int)blockIdx.x < nb);
    int b = roleD ? (int)blockIdx.x : (int)blockIdx.x - nb;
    int bs = b * CAPB;
    int be = bs + (roleD ? gcntD[b] : gcntS[b]);
    cnt[tid] = 0; cnt[tid + 256] = 0;
    __syncthreads();
    if (roleD) {
        for (int i = bs + tid; i < be; i += 256)
            atomicAdd(&cnt[packD[i] & 511], 1);
        __syncthreads();
        // exclusive scan over 512 node counts (pair trick with 256 threads)
        int a0 = cnt[2 * tid], a1 = cnt[2 * tid + 1];
        tmp[tid] = a0 + a1; __syncthreads();
        for (int off = 1; off < 256; off <<= 1) {
            int u = (tid >= off) ? tmp[tid - off] : 0; __syncthreads();
            tmp[tid] += u; __syncthreads();
        }
        int ex = tmp[tid] - (a0 + a1);
        lptr[2 * tid] = ex; lptr[2 * tid + 1] = ex + a0;
        __syncthreads();
        int v0 = b * SZ + tid, v1 = v0 + 256;
        if (v0 < n) {
            rowbeg[v0] = bs + lptr[tid];
            rowend[v0] = bs + lptr[tid] + cnt[tid];
            in_norm[v0] = rsqrtf((float)max(cnt[tid], 1));
        }
        if (v1 < n) {
            rowbeg[v1] = bs + lptr[tid + 256];
            rowend[v1] = bs + lptr[tid + 256] + cnt[tid + 256];
            in_norm[v1] = rsqrtf((float)max(cnt[tid + 256], 1));
        }
        __syncthreads();
        // fill packed CSR: slots via LDS cursor (lptr consumed)
        for (int i = bs + tid; i < be; i += 256) {
            unsigned p = packD[i];
            int slot = atomicAdd(&lptr[p & 511], 1);
            csr[bs + slot] = (int)(p >> 9);
        }
    } else {
        for (int i = bs + tid; i < be; i += 256)
            atomicAdd(&cnt[packS[i]], 1);
        __syncthreads();
        int v0 = b * SZ + tid, v1 = v0 + 256;
        if (v0 < n) out_norm[v0] = rsqrtf((float)max(cnt[tid], 1));
        if (v1 < n) out_norm[v1] = rsqrtf((float)max(cnt[tid + 256], 1));
    }
}

// ---------------- GEMM: Y = half(scale * (X @ W)), 64x64 LDS tile, 4x4/thread -------
// Xs: 16B-chunk XOR swizzle (chunk kq of row r at Xs[r*64 + ((kq^(r&15))<<2)]).
// __launch_bounds__(256,4): cap VGPR (round-2 lesson: uncapped -> 244 VGPR, 9% occ).
__global__ __launch_bounds__(256, 4) void gemm_kernel(
    const float* __restrict__ X, const float* __restrict__ W,
    const float* __restrict__ scale, __half* __restrict__ P, int n) {
    __shared__ float Ws[64 * 64];
    __shared__ float Xs[64 * 64];
    int tid = threadIdx.x;
    int row0 = (int)blockIdx.x * 64;
    if (row0 >= n) return;
    {
        const float4* W4 = (const float4*)W;
        float4* Ws4 = (float4*)Ws;
#pragma unroll
        for (int i = 0; i < 4; i++) Ws4[tid + 256 * i] = W4[tid + 256 * i];
    }
    {
#pragma unroll
        for (int i = 0; i < 4; i++) {
            int idx = tid + 256 * i;          // 0..1023 = 64 rows x 16 chunks
            int r = idx >> 4, kq = idx & 15;
            float4 v = make_float4(0.f, 0.f, 0.f, 0.f);
            int row = row0 + r;
            if (row < n) v = ((const float4*)X)[(size_t)row * 16 + kq];
            *(float4*)&Xs[r * 64 + ((kq ^ (r & 15)) << 2)] = v;
        }
    }
    __syncthreads();

    int tx = tid & 15, ty = tid >> 4;
    float acc[4][4] = {};
#pragma unroll 4
    for (int kc = 0; kc < 16; kc++) {
        float4 wv[4];
#pragma unroll
        for (int j = 0; j < 4; j++) wv[j] = *(float4*)&Ws[(4 * kc + j) * 64 + 4 * tx];
#pragma unroll
        for (int r = 0; r < 4; r++) {
            int row = 4 * ty + r;
            float4 xv = *(float4*)&Xs[row * 64 + ((kc ^ (row & 15)) << 2)];
            acc[r][0] = fmaf(xv.x, wv[0].x, acc[r][0]);
            acc[r][1] = fmaf(xv.x, wv[0].y, acc[r][1]);
            acc[r][2] = fmaf(xv.x, wv[0].z, acc[r][2]);
            acc[r][3] = fmaf(xv.x, wv[0].w, acc[r][3]);
            acc[r][0] = fmaf(xv.y, wv[1].x, acc[r][0]);
            acc[r][1] = fmaf(xv.y, wv[1].y, acc[r][1]);
            acc[r][2] = fmaf(xv.y, wv[1].z, acc[r][2]);
            acc[r][3] = fmaf(xv.y, wv[1].w, acc[r][3]);
            acc[r][0] = fmaf(xv.z, wv[2].x, acc[r][0]);
            acc[r][1] = fmaf(xv.z, wv[2].y, acc[r][1]);
            acc[r][2] = fmaf(xv.z, wv[2].z, acc[r][2]);
            acc[r][3] = fmaf(xv.z, wv[2].w, acc[r][3]);
            acc[r][0] = fmaf(xv.w, wv[3].x, acc[r][0]);
            acc[r][1] = fmaf(xv.w, wv[3].y, acc[r][1]);
            acc[r][2] = fmaf(xv.w, wv[3].z, acc[r][2]);
            acc[r][3] = fmaf(xv.w, wv[3].w, acc[r][3]);
        }
    }
#pragma unroll
    for (int r = 0; r < 4; r++) {
        int row = row0 + 4 * ty + r;
        if (row < n) {
            float sc = scale[row];
            uint2 o;
            o.x = h22u(__floats2half2_rn(acc[r][0] * sc, acc[r][1] * sc));
            o.y = h22u(__floats2half2_rn(acc[r][2] * sc, acc[r][3] * sc));
            *(uint2*)&P[(size_t)row * 64 + 4 * tx] = o;
        }
    }
}

// ---------------- fused gather + relu/norms + next-layer GEMM ----------------
// Phase 1 (round-3 gather): 8 lanes/node, full 128B row reads (round-4 lesson:
// partial-line slicing = 1.7x fetch amplification, no L2 affinity). Epilogue writes
// h = relu(agg*inv + b)*out_norm to LDS Hs[32][64].
// Phase 2: thread (vl,g) computes node vl's output features [8g,8g+8) against LDS W.
// Ws reads are 8-unique-address broadcasts across the wave (conflict-free-ish);
// the ~5us of VALU hides under the other waves' memory stalls (gather is 90% stall).
__global__ __launch_bounds__(256) void gather_gemm_kernel(
    const uint4* __restrict__ P4, const int* __restrict__ csr,
    const int* __restrict__ rowbeg, const int* __restrict__ rowend,
    const float* __restrict__ in_norm, const float* __restrict__ out_norm,
    const float* __restrict__ bias, const float* __restrict__ W,
    __half* __restrict__ Pout, int n) {
    __shared__ float Ws[64 * 64];   // 16 KB next-layer weights
    __shared__ float Hs[32 * 64];   // 8 KB hidden rows
    int tid = threadIdx.x;
    {
        const float4* W4 = (const float4*)W;
        float4* Ws4 = (float4*)Ws;
#pragma unroll
        for (int i = 0; i < 4; i++) Ws4[tid + 256 * i] = W4[tid + 256 * i];
    }
    int g = tid & 7;
    int base_lane = tid & 56;
    int vl = tid >> 3;
    int v = (int)blockIdx.x * 32 + vl;
    bool act = (v < n);

    if (act) {
        int begin = rowbeg[v];
        int end = rowend[v];
        float al0 = 0.f, al1 = 0.f, al2 = 0.f, al3 = 0.f;
        float ah0 = 0.f, ah1 = 0.f, ah2 = 0.f, ah3 = 0.f;
        for (int e = begin; e < end; e += 8) {
            int ee = e + g;
            int jl = (ee < end) ? csr[ee] : -1;       // coalesced idx read
            int js[8];
#pragma unroll
            for (int k = 0; k < 8; k++) js[k] = __shfl(jl, base_lane + k, 64);
            uint4 t[8];
#pragma unroll
            for (int k = 0; k < 8; k++) {
                t[k] = make_uint4(0u, 0u, 0u, 0u);
                if (js[k] >= 0) t[k] = P4[(size_t)js[k] * 8 + g];
            }
#pragma unroll
            for (int k = 0; k < 8; k++) {
                float2 f0 = __half22float2(u2h2(t[k].x));
                float2 f1 = __half22float2(u2h2(t[k].y));
                float2 f2 = __half22float2(u2h2(t[k].z));
                float2 f3 = __half22float2(u2h2(t[k].w));
                al0 += f0.x; al1 += f0.y; al2 += f1.x; al3 += f1.y;
                ah0 += f2.x; ah1 += f2.y; ah2 += f3.x; ah3 += f3.y;
            }
        }
        float inv = in_norm[v];
        float sc = out_norm[v];
        float4 blo = ((const float4*)bias)[2 * g];
        float4 bhi = ((const float4*)bias)[2 * g + 1];
        float4 h0, h1;
        h0.x = fmaxf(fmaf(al0, inv, blo.x), 0.f) * sc;
        h0.y = fmaxf(fmaf(al1, inv, blo.y), 0.f) * sc;
        h0.z = fmaxf(fmaf(al2, inv, blo.z), 0.f) * sc;
        h0.w = fmaxf(fmaf(al3, inv, blo.w), 0.f) * sc;
        h1.x = fmaxf(fmaf(ah0, inv, bhi.x), 0.f) * sc;
        h1.y = fmaxf(fmaf(ah1, inv, bhi.y), 0.f) * sc;
        h1.z = fmaxf(fmaf(ah2, inv, bhi.z), 0.f) * sc;
        h1.w = fmaxf(fmaf(ah3, inv, bhi.w), 0.f) * sc;
        *(float4*)&Hs[vl * 64 + 8 * g] = h0;
        *(float4*)&Hs[vl * 64 + 8 * g + 4] = h1;
    }
    __syncthreads();
    if (act) {
        float4 o0 = make_float4(0.f, 0.f, 0.f, 0.f);
        float4 o1 = make_float4(0.f, 0.f, 0.f, 0.f);
#pragma unroll 8
        for (int k = 0; k < 64; k++) {
            float h = Hs[vl * 64 + k];                    // wave broadcast
            float4 w0 = *(float4*)&Ws[k * 64 + 8 * g];    // 8-unique-addr broadcast
            float4 w1 = *(float4*)&Ws[k * 64 + 8 * g + 4];
            o0.x = fmaf(h, w0.x, o0.x); o0.y = fmaf(h, w0.y, o0.y);
            o0.z = fmaf(h, w0.z, o0.z); o0.w = fmaf(h, w0.w, o0.w);
            o1.x = fmaf(h, w1.x, o1.x); o1.y = fmaf(h, w1.y, o1.y);
            o1.z = fmaf(h, w1.z, o1.z); o1.w = fmaf(h, w1.w, o1.w);
        }
        uint4 t;
        t.x = h22u(__floats2half2_rn(o0.x, o0.y));
        t.y = h22u(__floats2half2_rn(o0.z, o0.w));
        t.z = h22u(__floats2half2_rn(o1.x, o1.y));
        t.w = h22u(__floats2half2_rn(o1.z, o1.w));
        ((uint4*)Pout)[(size_t)v * 8 + g] = t;            // coalesced 16B/lane
    }
}

// ---------------- final gather (no relu, fp32 out) ----------------
__global__ __launch_bounds__(256) void gather_kernel(
    const uint4* __restrict__ P4, const int* __restrict__ csr,
    const int* __restrict__ rowbeg, const int* __restrict__ rowend,
    const float* __restrict__ in_norm, const float* __restrict__ bias,
    float4* __restrict__ out4, int n) {
    int tid = threadIdx.x;
    int g = tid & 7;
    int base_lane = tid & 56;
    int v = blockIdx.x * 32 + (tid >> 3);
    if (v >= n) return;

    int begin = rowbeg[v];
    int end = rowend[v];
    float inv = in_norm[v];
    float4 blo = ((const float4*)bias)[2 * g];
    float4 bhi = ((const float4*)bias)[2 * g + 1];

    float al0 = 0.f, al1 = 0.f, al2 = 0.f, al3 = 0.f;
    float ah0 = 0.f, ah1 = 0.f, ah2 = 0.f, ah3 = 0.f;

    for (int e = begin; e < end; e += 8) {
        int ee = e + g;
        int jl = (ee < end) ? csr[ee] : -1;
        int js[8];
#pragma unroll
        for (int k = 0; k < 8; k++) js[k] = __shfl(jl, base_lane + k, 64);
        uint4 t[8];
#pragma unroll
        for (int k = 0; k < 8; k++) {
            t[k] = make_uint4(0u, 0u, 0u, 0u);
            if (js[k] >= 0) t[k] = P4[(size_t)js[k] * 8 + g];
        }
#pragma unroll
        for (int k = 0; k < 8; k++) {
            float2 f0 = __half22float2(u2h2(t[k].x));
            float2 f1 = __half22float2(u2h2(t[k].y));
            float2 f2 = __half22float2(u2h2(t[k].z));
            float2 f3 = __half22float2(u2h2(t[k].w));
            al0 += f0.x; al1 += f0.y; al2 += f1.x; al3 += f1.y;
            ah0 += f2.x; ah1 += f2.y; ah2 += f3.x; ah3 += f3.y;
        }
    }

    float4 o0, o1;
    o0.x = fmaf(al0, inv, blo.x); o0.y = fmaf(al1, inv, blo.y);
    o0.z = fmaf(al2, inv, blo.z); o0.w = fmaf(al3, inv, blo.w);
    o1.x = fmaf(ah0, inv, bhi.x); o1.y = fmaf(ah1, inv, bhi.y);
    o1.z = fmaf(ah2, inv, bhi.z); o1.w = fmaf(ah3, inv, bhi.w);
    out4[(size_t)v * 16 + 2 * g] = o0;
    out4[(size_t)v * 16 + 2 * g + 1] = o1;
}

// ---------------- launch ----------------

extern "C" void kernel_launch(void* const* d_in, const int* in_sizes, int n_in,
                              void* d_out, int out_size, void* d_ws, size_t ws_size,
                              hipStream_t stream) {
    const float* x  = (const float*)d_in[0];
    const int* src  = (const int*)d_in[1];
    const int* dst  = (const int*)d_in[2];
    const float* W1 = (const float*)d_in[3];
    const float* b1 = (const float*)d_in[4];
    const float* W2 = (const float*)d_in[5];
    const float* b2 = (const float*)d_in[6];
    const float* W3 = (const float*)d_in[7];
    const float* b3 = (const float*)d_in[8];

    const int N = in_sizes[0] / D;
    const int E = in_sizes[1];
    const int nb = (N + SZ - 1) / SZ;     // 196 buckets
    const int hb = (E + EPB - 1) / EPB;   // 977 scatter blocks

    char* ws = (char*)d_ws;
    size_t off = 0;
    auto alloc = [&](size_t bytes) -> void* {
        void* p = (void*)(ws + off);
        off += (bytes + 15) & ~(size_t)15;
        return p;
    };
    int* gcntD = (int*)alloc(256 * 4);   // contiguous with gcntS: one memset
    int* gcntS = (int*)alloc(256 * 4);
    unsigned* packD       = (unsigned*)alloc((size_t)nb * CAPB * 4);
    unsigned short* packS = (unsigned short*)alloc((size_t)nb * CAPB * 2);
    int* csr     = (int*)alloc((size_t)nb * CAPB * 4);
    int* rowbeg  = (int*)alloc((size_t)N * 4);
    int* rowend  = (int*)alloc((size_t)N * 4);
    float* innrm = (float*)alloc((size_t)N * 4);
    float* outnrm= (float*)alloc((size_t)N * 4);
    __half* bufPa = (__half*)alloc((size_t)N * D * 2);  // fp16 transformed feats
    __half* bufPb = (__half*)alloc((size_t)N * D * 2);  // ping-pong partner

    const int gemmb = (N + 63) / 64;             // 64-row LDS tiles
    const int sgrid = (N + 31) / 32;             // 32 nodes/block (8 lanes/node)

    hipMemsetAsync(gcntD, 0, 2 * 256 * sizeof(int), stream);

    // A: partition edges into per-bucket regions (global atomics: 2/(block,bucket))
    scatter_kernel<<<hb, 256, 0, stream>>>(src, dst, gcntD, gcntS,
                                           packD, packS, E, nb);
    // B: exact CSR + rowbeg/rowend + both norms, all coalesced
    build_kernel<<<2 * nb, 256, 0, stream>>>(packD, packS, gcntD, gcntS, csr,
                                             rowbeg, rowend, innrm, outnrm, N, nb);

    // layer 1: P1 = half(out_norm * (X @ W1)) — scale fused into GEMM epilogue
    gemm_kernel<<<gemmb, 256, 0, stream>>>(x, W1, outnrm, bufPa, N);
    // gather1 + relu/norm + @W2 fused -> P2 (fp16)
    gather_gemm_kernel<<<sgrid, 256, 0, stream>>>((const uint4*)bufPa, csr, rowbeg,
                                                  rowend, innrm, outnrm, b1, W2,
                                                  bufPb, N);
    // gather2 + relu/norm + @W3 fused -> P3 (fp16)
    gather_gemm_kernel<<<sgrid, 256, 0, stream>>>((const uint4*)bufPb, csr, rowbeg,
                                                  rowend, innrm, outnrm, b2, W3,
                                                  bufPa, N);
    // final gather: plain epilogue, fp32 out
    gather_kernel<<<sgrid, 256, 0, stream>>>((const uint4*)bufPa, csr, rowbeg,
                                             rowend, innrm, b3, (float4*)d_out, N);
}

// Round 6
// 235.018 us; speedup vs baseline: 1.7018x; 1.0280x over previous
//
#include <hip/hip_runtime.h>
#include <hip/hip_fp16.h>

#define D 64
#define SZ 512           // nodes per radix bucket (dst>>9 / src>>9)
#define EPB 2048         // edges per scatter block: 489 blocks, 192K reserve atomics
#define CAPB 8192        // slots per bucket region; Binom(1e6,1/196) max ~5500 << 8192
// Assumes N <= 131072 (src fits 17 bits, nb <= 256). Harness: N=100000, E=1000000.

static __device__ __forceinline__ __half2 u2h2(unsigned u) {
    union { unsigned u; __half2 h; } c; c.u = u; return c.h;
}
static __device__ __forceinline__ unsigned h22u(__half2 h) {
    union { __half2 h; unsigned u; } c; c.h = h; return c.u;
}

// ---------------- A: bucket-partition edges (LDS hist + edge stash; global atomics
// only at reserve: 2 per (block,bucket)). Bucket b owns region [b*CAPB, (b+1)*CAPB).
__global__ __launch_bounds__(256) void scatter_kernel(
    const int* __restrict__ src, const int* __restrict__ dst,
    int* __restrict__ gcntD, int* __restrict__ gcntS,
    unsigned* __restrict__ packD, unsigned short* __restrict__ packS,
    int E, int nb) {
    int tid = threadIdx.x;
    __shared__ int hD[256], hS[256], baseD[256], baseS[256], curD[256], curS[256];
    __shared__ int es[EPB], ed[EPB];   // edge stash: pass 2 reads LDS, not global
    hD[tid] = 0; hS[tid] = 0; curD[tid] = 0; curS[tid] = 0;
    __syncthreads();
    int ebase = (int)blockIdx.x * EPB;
#pragma unroll
    for (int k = 0; k < EPB / 256; k++) {
        int e = ebase + k * 256 + tid;
        int s = -1, d = 0;
        if (e < E) { s = src[e]; d = dst[e]; }
        es[k * 256 + tid] = s;
        ed[k * 256 + tid] = d;
        if (s >= 0) {
            atomicAdd(&hD[d >> 9], 1);
            atomicAdd(&hS[s >> 9], 1);
        }
    }
    __syncthreads();
    if (tid < nb) {
        int c = hD[tid];
        baseD[tid] = tid * CAPB + (c ? atomicAdd(&gcntD[tid], c) : 0);
        c = hS[tid];
        baseS[tid] = tid * CAPB + (c ? atomicAdd(&gcntS[tid], c) : 0);
    }
    __syncthreads();
#pragma unroll
    for (int k = 0; k < EPB / 256; k++) {
        int s = es[k * 256 + tid];
        if (s >= 0) {
            int d = ed[k * 256 + tid];
            int bd = d >> 9, bs_ = s >> 9;
            int ld = atomicAdd(&curD[bd], 1);
            int ls = atomicAdd(&curS[bs_], 1);
            packD[baseD[bd] + ld] = ((unsigned)s << 9) | (unsigned)(d & 511);
            packS[baseS[bs_] + ls] = (unsigned short)(s & 511);
        }
    }
}

// ---------------- B: per-bucket CSR build + norms (coalesced) ----------------
// Blocks [0,nb): dst role -> rowbeg/rowend, csr, in_norm. Blocks [nb,2nb): out_norm.
__global__ __launch_bounds__(256) void build_kernel(
    const unsigned* __restrict__ packD, const unsigned short* __restrict__ packS,
    const int* __restrict__ gcntD, const int* __restrict__ gcntS,
    int* __restrict__ csr, int* __restrict__ rowbeg, int* __restrict__ rowend,
    float* __restrict__ in_norm, float* __restrict__ out_norm,
    int n, int nb) {
    int tid = threadIdx.x;
    __shared__ int cnt[512], lptr[512], tmp[256];
    bool roleD = ((int)blockIdx.x < nb);
    int b = roleD ? (int)blockIdx.x : (int)blockIdx.x - nb;
    int bs = b * CAPB;
    int be = bs + (roleD ? gcntD[b] : gcntS[b]);
    cnt[tid] = 0; cnt[tid + 256] = 0;
    __syncthreads();
    if (roleD) {
        for (int i = bs + tid; i < be; i += 256)
            atomicAdd(&cnt[packD[i] & 511], 1);
        __syncthreads();
        // exclusive scan over 512 node counts (pair trick with 256 threads)
        int a0 = cnt[2 * tid], a1 = cnt[2 * tid + 1];
        tmp[tid] = a0 + a1; __syncthreads();
        for (int off = 1; off < 256; off <<= 1) {
            int u = (tid >= off) ? tmp[tid - off] : 0; __syncthreads();
            tmp[tid] += u; __syncthreads();
        }
        int ex = tmp[tid] - (a0 + a1);
        lptr[2 * tid] = ex; lptr[2 * tid + 1] = ex + a0;
        __syncthreads();
        int v0 = b * SZ + tid, v1 = v0 + 256;
        if (v0 < n) {
            rowbeg[v0] = bs + lptr[tid];
            rowend[v0] = bs + lptr[tid] + cnt[tid];
            in_norm[v0] = rsqrtf((float)max(cnt[tid], 1));
        }
        if (v1 < n) {
            rowbeg[v1] = bs + lptr[tid + 256];
            rowend[v1] = bs + lptr[tid + 256] + cnt[tid + 256];
            in_norm[v1] = rsqrtf((float)max(cnt[tid + 256], 1));
        }
        __syncthreads();
        // fill packed CSR: slots via LDS cursor (lptr consumed)
        for (int i = bs + tid; i < be; i += 256) {
            unsigned p = packD[i];
            int slot = atomicAdd(&lptr[p & 511], 1);
            csr[bs + slot] = (int)(p >> 9);
        }
    } else {
        for (int i = bs + tid; i < be; i += 256)
            atomicAdd(&cnt[packS[i]], 1);
        __syncthreads();
        int v0 = b * SZ + tid, v1 = v0 + 256;
        if (v0 < n) out_norm[v0] = rsqrtf((float)max(cnt[tid], 1));
        if (v1 < n) out_norm[v1] = rsqrtf((float)max(cnt[tid + 256], 1));
    }
}

// ---------------- GEMM: Y = half(scale * (X @ W)), 64x64 LDS tile, 4x4/thread -------
// Xs: 16B-chunk XOR swizzle (chunk kq of row r at Xs[r*64 + ((kq^(r&15))<<2)]).
// __launch_bounds__(256,4): cap VGPR (round-2 lesson: uncapped -> 244 VGPR, 9% occ).
__global__ __launch_bounds__(256, 4) void gemm_kernel(
    const float* __restrict__ X, const float* __restrict__ W,
    const float* __restrict__ scale, __half* __restrict__ P, int n) {
    __shared__ float Ws[64 * 64];
    __shared__ float Xs[64 * 64];
    int tid = threadIdx.x;
    int row0 = (int)blockIdx.x * 64;
    if (row0 >= n) return;
    {
        const float4* W4 = (const float4*)W;
        float4* Ws4 = (float4*)Ws;
#pragma unroll
        for (int i = 0; i < 4; i++) Ws4[tid + 256 * i] = W4[tid + 256 * i];
    }
    {
#pragma unroll
        for (int i = 0; i < 4; i++) {
            int idx = tid + 256 * i;          // 0..1023 = 64 rows x 16 chunks
            int r = idx >> 4, kq = idx & 15;
            float4 v = make_float4(0.f, 0.f, 0.f, 0.f);
            int row = row0 + r;
            if (row < n) v = ((const float4*)X)[(size_t)row * 16 + kq];
            *(float4*)&Xs[r * 64 + ((kq ^ (r & 15)) << 2)] = v;
        }
    }
    __syncthreads();

    int tx = tid & 15, ty = tid >> 4;
    float acc[4][4] = {};
#pragma unroll 4
    for (int kc = 0; kc < 16; kc++) {
        float4 wv[4];
#pragma unroll
        for (int j = 0; j < 4; j++) wv[j] = *(float4*)&Ws[(4 * kc + j) * 64 + 4 * tx];
#pragma unroll
        for (int r = 0; r < 4; r++) {
            int row = 4 * ty + r;
            float4 xv = *(float4*)&Xs[row * 64 + ((kc ^ (row & 15)) << 2)];
            acc[r][0] = fmaf(xv.x, wv[0].x, acc[r][0]);
            acc[r][1] = fmaf(xv.x, wv[0].y, acc[r][1]);
            acc[r][2] = fmaf(xv.x, wv[0].z, acc[r][2]);
            acc[r][3] = fmaf(xv.x, wv[0].w, acc[r][3]);
            acc[r][0] = fmaf(xv.y, wv[1].x, acc[r][0]);
            acc[r][1] = fmaf(xv.y, wv[1].y, acc[r][1]);
            acc[r][2] = fmaf(xv.y, wv[1].z, acc[r][2]);
            acc[r][3] = fmaf(xv.y, wv[1].w, acc[r][3]);
            acc[r][0] = fmaf(xv.z, wv[2].x, acc[r][0]);
            acc[r][1] = fmaf(xv.z, wv[2].y, acc[r][1]);
            acc[r][2] = fmaf(xv.z, wv[2].z, acc[r][2]);
            acc[r][3] = fmaf(xv.z, wv[2].w, acc[r][3]);
            acc[r][0] = fmaf(xv.w, wv[3].x, acc[r][0]);
            acc[r][1] = fmaf(xv.w, wv[3].y, acc[r][1]);
            acc[r][2] = fmaf(xv.w, wv[3].z, acc[r][2]);
            acc[r][3] = fmaf(xv.w, wv[3].w, acc[r][3]);
        }
    }
#pragma unroll
    for (int r = 0; r < 4; r++) {
        int row = row0 + 4 * ty + r;
        if (row < n) {
            float sc = scale[row];
            uint2 o;
            o.x = h22u(__floats2half2_rn(acc[r][0] * sc, acc[r][1] * sc));
            o.y = h22u(__floats2half2_rn(acc[r][2] * sc, acc[r][3] * sc));
            *(uint2*)&P[(size_t)row * 64 + 4 * tx] = o;
        }
    }
}

// ---------------- fused gather + relu/norms + next-layer GEMM (barrier-free) --------
// Phase 1: 8 lanes/node, full 128B row reads (round-4 lesson: partial-line slicing
// amplifies fetch 1.7x). h = relu(agg*inv + b)*out_norm kept in REGISTERS hr[8].
// Phase 2: o[8g+i] = sum_k h[k]*W[k][8g+i]; h[k] obtained via 64 statically-indexed
// __shfl within the 8-lane group (round-5 lesson: LDS Hs was 8-way bank-conflicted
// and the mid-kernel __syncthreads made all waves wait on the max-degree node).
// Only barrier is after the W staging at kernel start. LDS 16KB -> high occupancy.
__global__ __launch_bounds__(256) void gather_gemm_kernel(
    const uint4* __restrict__ P4, const int* __restrict__ csr,
    const int* __restrict__ rowbeg, const int* __restrict__ rowend,
    const float* __restrict__ in_norm, const float* __restrict__ out_norm,
    const float* __restrict__ bias, const float* __restrict__ W,
    __half* __restrict__ Pout, int n) {
    __shared__ float Ws[64 * 64];   // 16 KB next-layer weights
    int tid = threadIdx.x;
    {
        const float4* W4 = (const float4*)W;
        float4* Ws4 = (float4*)Ws;
#pragma unroll
        for (int i = 0; i < 4; i++) Ws4[tid + 256 * i] = W4[tid + 256 * i];
    }
    __syncthreads();                // the only barrier

    int g = tid & 7;
    int base_lane = tid & 56;
    int v = (int)blockIdx.x * 32 + (tid >> 3);
    if (v >= n) return;             // whole 8-lane group exits together (same v)

    int begin = rowbeg[v];
    int end = rowend[v];
    float al0 = 0.f, al1 = 0.f, al2 = 0.f, al3 = 0.f;
    float ah0 = 0.f, ah1 = 0.f, ah2 = 0.f, ah3 = 0.f;
    for (int e = begin; e < end; e += 8) {
        int ee = e + g;
        int jl = (ee < end) ? csr[ee] : -1;       // coalesced idx read
        int js[8];
#pragma unroll
        for (int k = 0; k < 8; k++) js[k] = __shfl(jl, base_lane + k, 64);
        uint4 t[8];
#pragma unroll
        for (int k = 0; k < 8; k++) {
            t[k] = make_uint4(0u, 0u, 0u, 0u);
            if (js[k] >= 0) t[k] = P4[(size_t)js[k] * 8 + g];
        }
#pragma unroll
        for (int k = 0; k < 8; k++) {
            float2 f0 = __half22float2(u2h2(t[k].x));
            float2 f1 = __half22float2(u2h2(t[k].y));
            float2 f2 = __half22float2(u2h2(t[k].z));
            float2 f3 = __half22float2(u2h2(t[k].w));
            al0 += f0.x; al1 += f0.y; al2 += f1.x; al3 += f1.y;
            ah0 += f2.x; ah1 += f2.y; ah2 += f3.x; ah3 += f3.y;
        }
    }
    float inv = in_norm[v];
    float sc = out_norm[v];
    float4 blo = ((const float4*)bias)[2 * g];
    float4 bhi = ((const float4*)bias)[2 * g + 1];
    float hr[8];
    hr[0] = fmaxf(fmaf(al0, inv, blo.x), 0.f) * sc;
    hr[1] = fmaxf(fmaf(al1, inv, blo.y), 0.f) * sc;
    hr[2] = fmaxf(fmaf(al2, inv, blo.z), 0.f) * sc;
    hr[3] = fmaxf(fmaf(al3, inv, blo.w), 0.f) * sc;
    hr[4] = fmaxf(fmaf(ah0, inv, bhi.x), 0.f) * sc;
    hr[5] = fmaxf(fmaf(ah1, inv, bhi.y), 0.f) * sc;
    hr[6] = fmaxf(fmaf(ah2, inv, bhi.z), 0.f) * sc;
    hr[7] = fmaxf(fmaf(ah3, inv, bhi.w), 0.f) * sc;

    // phase 2: this lane computes output feats [8g, 8g+8) for node v.
    // Ws reads: 8 distinct addrs @ 32B stride per instruction -> 2-way (free).
    float o[8];
#pragma unroll
    for (int i = 0; i < 8; i++) o[i] = 0.f;
#pragma unroll
    for (int gp = 0; gp < 8; gp++) {
#pragma unroll
        for (int ip = 0; ip < 8; ip++) {
            float hk = __shfl(hr[ip], base_lane + gp, 64);   // static reg index
            const float* wrow = &Ws[(8 * gp + ip) * 64 + 8 * g];
            float4 w0 = *(const float4*)wrow;
            float4 w1 = *(const float4*)(wrow + 4);
            o[0] = fmaf(hk, w0.x, o[0]); o[1] = fmaf(hk, w0.y, o[1]);
            o[2] = fmaf(hk, w0.z, o[2]); o[3] = fmaf(hk, w0.w, o[3]);
            o[4] = fmaf(hk, w1.x, o[4]); o[5] = fmaf(hk, w1.y, o[5]);
            o[6] = fmaf(hk, w1.z, o[6]); o[7] = fmaf(hk, w1.w, o[7]);
        }
    }
    uint4 t;
    t.x = h22u(__floats2half2_rn(o[0], o[1]));
    t.y = h22u(__floats2half2_rn(o[2], o[3]));
    t.z = h22u(__floats2half2_rn(o[4], o[5]));
    t.w = h22u(__floats2half2_rn(o[6], o[7]));
    ((uint4*)Pout)[(size_t)v * 8 + g] = t;                   // coalesced 16B/lane
}

// ---------------- final gather (no relu, fp32 out) ----------------
__global__ __launch_bounds__(256) void gather_kernel(
    const uint4* __restrict__ P4, const int* __restrict__ csr,
    const int* __restrict__ rowbeg, const int* __restrict__ rowend,
    const float* __restrict__ in_norm, const float* __restrict__ bias,
    float4* __restrict__ out4, int n) {
    int tid = threadIdx.x;
    int g = tid & 7;
    int base_lane = tid & 56;
    int v = blockIdx.x * 32 + (tid >> 3);
    if (v >= n) return;

    int begin = rowbeg[v];
    int end = rowend[v];
    float inv = in_norm[v];
    float4 blo = ((const float4*)bias)[2 * g];
    float4 bhi = ((const float4*)bias)[2 * g + 1];

    float al0 = 0.f, al1 = 0.f, al2 = 0.f, al3 = 0.f;
    float ah0 = 0.f, ah1 = 0.f, ah2 = 0.f, ah3 = 0.f;

    for (int e = begin; e < end; e += 8) {
        int ee = e + g;
        int jl = (ee < end) ? csr[ee] : -1;
        int js[8];
#pragma unroll
        for (int k = 0; k < 8; k++) js[k] = __shfl(jl, base_lane + k, 64);
        uint4 t[8];
#pragma unroll
        for (int k = 0; k < 8; k++) {
            t[k] = make_uint4(0u, 0u, 0u, 0u);
            if (js[k] >= 0) t[k] = P4[(size_t)js[k] * 8 + g];
        }
#pragma unroll
        for (int k = 0; k < 8; k++) {
            float2 f0 = __half22float2(u2h2(t[k].x));
            float2 f1 = __half22float2(u2h2(t[k].y));
            float2 f2 = __half22float2(u2h2(t[k].z));
            float2 f3 = __half22float2(u2h2(t[k].w));
            al0 += f0.x; al1 += f0.y; al2 += f1.x; al3 += f1.y;
            ah0 += f2.x; ah1 += f2.y; ah2 += f3.x; ah3 += f3.y;
        }
    }

    float4 o0, o1;
    o0.x = fmaf(al0, inv, blo.x); o0.y = fmaf(al1, inv, blo.y);
    o0.z = fmaf(al2, inv, blo.z); o0.w = fmaf(al3, inv, blo.w);
    o1.x = fmaf(ah0, inv, bhi.x); o1.y = fmaf(ah1, inv, bhi.y);
    o1.z = fmaf(ah2, inv, bhi.z); o1.w = fmaf(ah3, inv, bhi.w);
    out4[(size_t)v * 16 + 2 * g] = o0;
    out4[(size_t)v * 16 + 2 * g + 1] = o1;
}

// ---------------- launch ----------------

extern "C" void kernel_launch(void* const* d_in, const int* in_sizes, int n_in,
                              void* d_out, int out_size, void* d_ws, size_t ws_size,
                              hipStream_t stream) {
    const float* x  = (const float*)d_in[0];
    const int* src  = (const int*)d_in[1];
    const int* dst  = (const int*)d_in[2];
    const float* W1 = (const float*)d_in[3];
    const float* b1 = (const float*)d_in[4];
    const float* W2 = (const float*)d_in[5];
    const float* b2 = (const float*)d_in[6];
    const float* W3 = (const float*)d_in[7];
    const float* b3 = (const float*)d_in[8];

    const int N = in_sizes[0] / D;
    const int E = in_sizes[1];
    const int nb = (N + SZ - 1) / SZ;     // 196 buckets
    const int hb = (E + EPB - 1) / EPB;   // 489 scatter blocks

    char* ws = (char*)d_ws;
    size_t off = 0;
    auto alloc = [&](size_t bytes) -> void* {
        void* p = (void*)(ws + off);
        off += (bytes + 15) & ~(size_t)15;
        return p;
    };
    int* gcntD = (int*)alloc(256 * 4);   // contiguous with gcntS: one memset
    int* gcntS = (int*)alloc(256 * 4);
    unsigned* packD       = (unsigned*)alloc((size_t)nb * CAPB * 4);
    unsigned short* packS = (unsigned short*)alloc((size_t)nb * CAPB * 2);
    int* csr     = (int*)alloc((size_t)nb * CAPB * 4);
    int* rowbeg  = (int*)alloc((size_t)N * 4);
    int* rowend  = (int*)alloc((size_t)N * 4);
    float* innrm = (float*)alloc((size_t)N * 4);
    float* outnrm= (float*)alloc((size_t)N * 4);
    __half* bufPa = (__half*)alloc((size_t)N * D * 2);  // fp16 transformed feats
    __half* bufPb = (__half*)alloc((size_t)N * D * 2);  // ping-pong partner

    const int gemmb = (N + 63) / 64;             // 64-row LDS tiles
    const int sgrid = (N + 31) / 32;             // 32 nodes/block (8 lanes/node)

    hipMemsetAsync(gcntD, 0, 2 * 256 * sizeof(int), stream);

    // A: partition edges into per-bucket regions
    scatter_kernel<<<hb, 256, 0, stream>>>(src, dst, gcntD, gcntS,
                                           packD, packS, E, nb);
    // B: exact CSR + rowbeg/rowend + both norms, all coalesced
    build_kernel<<<2 * nb, 256, 0, stream>>>(packD, packS, gcntD, gcntS, csr,
                                             rowbeg, rowend, innrm, outnrm, N, nb);

    // layer 1: P1 = half(out_norm * (X @ W1)) — scale fused into GEMM epilogue
    gemm_kernel<<<gemmb, 256, 0, stream>>>(x, W1, outnrm, bufPa, N);
    // gather1 + relu/norm + @W2 fused -> P2 (fp16)
    gather_gemm_kernel<<<sgrid, 256, 0, stream>>>((const uint4*)bufPa, csr, rowbeg,
                                                  rowend, innrm, outnrm, b1, W2,
                                                  bufPb, N);
    // gather2 + relu/norm + @W3 fused -> P3 (fp16)
    gather_gemm_kernel<<<sgrid, 256, 0, stream>>>((const uint4*)bufPb, csr, rowbeg,
                                                  rowend, innrm, outnrm, b2, W3,
                                                  bufPa, N);
    // final gather: plain epilogue, fp32 out
    gather_kernel<<<sgrid, 256, 0, stream>>>((const uint4*)bufPa, csr, rowbeg,
                                             rowend, innrm, b3, (float4*)d_out, N);
}